// Round 16
// baseline (439.416 us; speedup 1.0000x reference)
//
#include <hip/hip_runtime.h>

#define TOK 4096
#define HD 1024
#define ID 4096
#define NE 8
#define MAXT1 24  // 256-row tiles: sum ceil(ne/256) <= 16+8
#define MAXT2 40  // 128-row tiles: sum ceil(ne/128) <= 32+8

typedef __attribute__((ext_vector_type(4))) float f32x4;
typedef __attribute__((ext_vector_type(8))) __bf16 bf16x8;

typedef const __attribute__((address_space(1))) void* gas1_t;
typedef __attribute__((address_space(3))) void* las3_t;

// async global->LDS DMA, 16B/lane; LDS dest = wave-uniform base + lane*16 (linear).
// Swizzle applied on per-lane GLOBAL source (rule 21 / m173).
__device__ __forceinline__ void dma16(const void* g, void* l) {
  __builtin_amdgcn_global_load_lds((gas1_t)g, (las3_t)l, 16, 0, 0);
}

// compiler emits v_cvt_pk_bf16_f32 (RNE) for scalar casts (m240)
__device__ __forceinline__ bf16x8 pack8(f32x4 a, f32x4 b) {
  bf16x8 r;
#pragma unroll
  for (int i = 0; i < 4; ++i) { r[i] = (__bf16)a[i]; r[i + 4] = (__bf16)b[i]; }
  return r;
}

__device__ __forceinline__ float gelu_tanh(float g) {
  float z = 0.7978845608028654f * (g + 0.044715f * g * g * g);
  float t = __expf(-2.0f * z);
  return g / (1.0f + t);
}

__device__ __forceinline__ void bar_lgkm() {
  asm volatile("s_waitcnt lgkmcnt(0)" ::: "memory");
  __builtin_amdgcn_s_barrier();
}
__device__ __forceinline__ void wait_vm12() {
  asm volatile("s_waitcnt vmcnt(12)" ::: "memory");
}
__device__ __forceinline__ void wait_vm0() {
  asm volatile("s_waitcnt vmcnt(0)" ::: "memory");
}

__global__ void init_k(int* __restrict__ meta) {
  if (threadIdx.x < 16) meta[threadIdx.x] = 0;
}

// one wave per token: fp32 logits (argmax must match numpy fp32)
__global__ void router_k(const float* __restrict__ x, const float* __restrict__ gw,
                         float* __restrict__ logits, int* __restrict__ top1) {
  const int wid = threadIdx.x >> 6;
  const int lane = threadIdx.x & 63;
  const int t = blockIdx.x * 4 + wid;
  const float* xr = x + (size_t)t * HD;
  float acc[NE];
#pragma unroll
  for (int e = 0; e < NE; ++e) acc[e] = 0.0f;
#pragma unroll
  for (int c = 0; c < 4; ++c) {
    const int k = (c * 64 + lane) * 4;
    f32x4 xv = *(const f32x4*)(xr + k);
#pragma unroll
    for (int e = 0; e < NE; ++e) {
      f32x4 gv = *(const f32x4*)(gw + e * HD + k);
      acc[e] += xv[0] * gv[0] + xv[1] * gv[1] + xv[2] * gv[2] + xv[3] * gv[3];
    }
  }
#pragma unroll
  for (int off = 32; off > 0; off >>= 1) {
#pragma unroll
    for (int e = 0; e < NE; ++e) acc[e] += __shfl_xor(acc[e], off, 64);
  }
  if (lane == 0) {
    int best = 0; float bv = acc[0];
#pragma unroll
    for (int e = 1; e < NE; ++e) if (acc[e] > bv) { bv = acc[e]; best = e; }
    top1[t] = best;
#pragma unroll
    for (int e = 0; e < NE; ++e) logits[(size_t)t * NE + e] = acc[e];
  }
}

__global__ void hist_k(const int* __restrict__ top1, int* __restrict__ counts) {
  int t = blockIdx.x * 256 + threadIdx.x;
  atomicAdd(&counts[top1[t]], 1);
}

// offsets + two compacted tile maps (256-row for gemm1, 128-row for gemm2)
__global__ void offsets_k(const int* __restrict__ counts, int* __restrict__ offsets,
                          int* __restrict__ tm1, int* __restrict__ nt1,
                          int* __restrict__ tm2, int* __restrict__ nt2) {
  if (threadIdx.x == 0) {
    int s = 0;
    for (int e = 0; e < NE; ++e) { offsets[e] = s; s += counts[e]; }
    int a = 0, b = 0;
    for (int e = 0; e < NE; ++e) {
      int n1 = (counts[e] + 255) >> 8;
      for (int i = 0; i < n1; ++i) tm1[a++] = (e << 8) | i;
      int n2 = (counts[e] + 127) >> 7;
      for (int i = 0; i < n2; ++i) tm2[b++] = (e << 8) | i;
    }
    *nt1 = a;
    *nt2 = b;
  }
}

__global__ void scatter_k(const int* __restrict__ top1, const int* __restrict__ offsets,
                          int* __restrict__ counts2, int* __restrict__ perm) {
  int t = blockIdx.x * 256 + threadIdx.x;
  int e = top1[t];
  int slot = atomicAdd(&counts2[e], 1);
  perm[offsets[e] + slot] = t;
}

// compact permuted bf16 copy of x
__global__ void xp_k(const float* __restrict__ x, const int* __restrict__ perm,
                     unsigned short* __restrict__ xp) {
  const int p = blockIdx.x * 4 + (threadIdx.x >> 6);
  const int lane = threadIdx.x & 63;
  const float* src = x + (size_t)perm[p] * HD + lane * 16;
  unsigned short* dst = xp + (size_t)p * HD + lane * 16;
  f32x4 v0 = *(const f32x4*)(src);
  f32x4 v1 = *(const f32x4*)(src + 4);
  f32x4 v2 = *(const f32x4*)(src + 8);
  f32x4 v3 = *(const f32x4*)(src + 12);
  *(bf16x8*)(dst) = pack8(v0, v1);
  *(bf16x8*)(dst + 8) = pack8(v2, v3);
}

// gemm1: BM=256 tok x 128 out-cols (gate || up), BK=64. 512 thr / 8 waves = 2wm x 4wn,
// wave tile 128x64 (acc 8x4 = 128 AGPR) -> 43.7 FLOP per LDS-read-byte (m201 geometry).
// A: xp bf16 via gload_lds DMA (src-swizzled). B: fp32->bf16 reg-staged (T14: loads
// issued 1.5 tiles early, writes after barrier). Counted vmcnt(12): A-dma for next
// tile + B-loads for tile+2 stay in flight across barriers. LDS 128KB, 1 block/CU.
// Gate/up fused via full-LDS f32 exchange epilogue.
__global__ __launch_bounds__(512, 2) void gemm1_k(
    const unsigned short* __restrict__ xp, const float* __restrict__ wg,
    const float* __restrict__ wu, const int* __restrict__ counts,
    const int* __restrict__ offsets, const int* __restrict__ tm1,
    const int* __restrict__ nt1, unsigned short* __restrict__ hidden) {
  const int t = blockIdx.x >> 5;
  const int nt = blockIdx.x & 31;          // 32 panels of 128 cols; siblings bid+=32 -> same XCD
  if (t >= *nt1) return;
  const int tm = tm1[t];
  const int e = tm >> 8, mt = tm & 255;
  const int ne = counts[e];
  const int off = offsets[e];

  __shared__ __align__(16) char lds[131072];  // A: P*32768; B: 65536 + P*32768

  const int tid = threadIdx.x;
  const int lane = tid & 63;
  const int wid = tid >> 6;
  const int wm = wid >> 2;                 // 0..1 -> rows wm*128
  const int wn = wid & 3;                  // 0,1 = gate cols; 2,3 = up cols
  const int frow = lane & 15;
  const int fk = lane >> 4;

  // A DMA sources: instr i: rows wid*32 + i*8 + (lane>>3), phys slot lane&7,
  // global slot = (lane&7) ^ (row&7)
  const char* aSrc[4];
#pragma unroll
  for (int i = 0; i < 4; ++i) {
    const int row = wid * 32 + i * 8 + (lane >> 3);
    int tr = off + mt * 256 + row;
    if (tr >= TOK) tr = TOK - 1;           // masked at store
    aSrc[i] = (const char*)xp + (size_t)tr * 2048 + (((lane & 7) ^ (row & 7)) << 4);
  }
  // B source: thread covers half-row (32 fp32). rows 0-127 gate, 128-255 up.
  const int brow = tid >> 1, bhalf = tid & 1;
  const float* bSrc = ((brow < 128)
      ? wg + ((size_t)e * ID + nt * 128 + brow) * HD
      : wu + ((size_t)e * ID + nt * 128 + (brow - 128)) * HD) + bhalf * 32;

  f32x4 acc[8][4] = {};
  f32x4 rB[8];

#define G1_LOADB(kt)                                                      \
  do {                                                                    \
    const float* s_ = bSrc + (kt) * 64;                                   \
    _Pragma("unroll") for (int i = 0; i < 8; ++i)                         \
      rB[i] = *(const f32x4*)(s_ + i * 4);                                \
  } while (0)

#define G1_WRITEB(P)                                                      \
  do {                                                                    \
    _Pragma("unroll") for (int i = 0; i < 4; ++i) {                       \
      const int ls_ = (bhalf * 4 + i) ^ (brow & 7);                       \
      *(bf16x8*)(lds + 65536 + (P) * 32768 + brow * 128 + (ls_ << 4)) =   \
          pack8(rB[2 * i], rB[2 * i + 1]);                                \
    }                                                                     \
  } while (0)

#define G1_ISSUE_A(kt, P)                                                 \
  do {                                                                    \
    _Pragma("unroll") for (int i = 0; i < 4; ++i)                         \
      dma16(aSrc[i] + (size_t)(kt) * 128, lds + (P) * 32768 + wid * 4096 + i * 1024); \
  } while (0)

#define G1_COMP(P)                                                        \
  do {                                                                    \
    _Pragma("unroll") for (int h = 0; h < 2; ++h) {                       \
      bf16x8 bb[4];                                                       \
      _Pragma("unroll") for (int ni = 0; ni < 4; ++ni) {                  \
        const int rb_ = wn * 64 + ni * 16 + frow;                         \
        bb[ni] = *(const bf16x8*)(lds + 65536 + (P) * 32768 + rb_ * 128 + \
                                  (((h * 4 + fk) ^ (rb_ & 7)) << 4));     \
      }                                                                   \
      _Pragma("unroll") for (int mh = 0; mh < 2; ++mh) {                  \
        bf16x8 af[4];                                                     \
        _Pragma("unroll") for (int q = 0; q < 4; ++q) {                   \
          const int ra_ = wm * 128 + (mh * 4 + q) * 16 + frow;            \
          af[q] = *(const bf16x8*)(lds + (P) * 32768 + ra_ * 128 +        \
                                   (((h * 4 + fk) ^ (ra_ & 7)) << 4));    \
        }                                                                 \
        __builtin_amdgcn_s_setprio(1);                                    \
        _Pragma("unroll") for (int q = 0; q < 4; ++q)                     \
          _Pragma("unroll") for (int ni = 0; ni < 4; ++ni)                \
            acc[mh * 4 + q][ni] = __builtin_amdgcn_mfma_f32_16x16x32_bf16( \
                af[q], bb[ni], acc[mh * 4 + q][ni], 0, 0, 0);             \
        __builtin_amdgcn_s_setprio(0);                                    \
      }                                                                   \
    }                                                                     \
  } while (0)

  const int NIT = HD / 64;  // 16
  // prologue: queue = LB0[8], A0[4], LB1[8], A1[4]
  G1_LOADB(0);
  G1_ISSUE_A(0, 0);
  G1_WRITEB(0);            // compiler waits LB0 (vmcnt(16))
  G1_LOADB(1);
  G1_ISSUE_A(1, 1);
  wait_vm12();             // drains A0; LB1+A1 stay in flight
  bar_lgkm();              // buf0 ready

  for (int kt = 0; kt < NIT; ++kt) {
    const int P = kt & 1;
    if (kt + 1 < NIT) G1_WRITEB(P ^ 1);    // waits only its B-loads (deep-covered)
    G1_COMP(P);
    if (kt + 2 < NIT) G1_LOADB(kt + 2);
    bar_lgkm();                             // all waves done reading bufP; B writes drained
    if (kt + 2 < NIT) {
      G1_ISSUE_A(kt + 2, P);
      wait_vm12();                          // drains A(kt+1); LB(kt+2)+A(kt+2) in flight
    } else {
      wait_vm0();
    }
    __builtin_amdgcn_s_barrier();           // buf(P^1) = tile kt+1 fully ready
  }
#undef G1_LOADB
#undef G1_WRITEB
#undef G1_ISSUE_A
#undef G1_COMP

  // epilogue: gate waves -> f32 exchange in the (dead) 128KB LDS; up waves fuse.
  __syncthreads();
  float* ex = (float*)lds;   // [256][128]
  if (wn < 2) {
#pragma unroll
    for (int mi = 0; mi < 8; ++mi)
#pragma unroll
      for (int ni = 0; ni < 4; ++ni)
#pragma unroll
        for (int j = 0; j < 4; ++j) {
          const int row = wm * 128 + mi * 16 + fk * 4 + j;
          ex[row * 128 + wn * 64 + ni * 16 + frow] = acc[mi][ni][j];
        }
  }
  __syncthreads();
  if (wn >= 2) {
#pragma unroll
    for (int mi = 0; mi < 8; ++mi)
#pragma unroll
      for (int j = 0; j < 4; ++j) {
        const int row = wm * 128 + mi * 16 + fk * 4 + j;
        const int grow = mt * 256 + row;
        if (grow < ne) {
          unsigned short* hrow = hidden + (size_t)(off + grow) * ID + nt * 128 + (wn - 2) * 64;
#pragma unroll
          for (int ni = 0; ni < 4; ++ni) {
            const int col = ni * 16 + frow;
            float g = ex[row * 128 + (wn - 2) * 64 + col];
            __bf16 hb = (__bf16)(gelu_tanh(g) * acc[mi][ni][j]);
            hrow[col] = __builtin_bit_cast(unsigned short, hb);
          }
        }
      }
  }
}

// gemm2: out[token] = hidden[p] @ wd[e]^T. BM=128 x BN=128, BK=64, 256 thr / 4 waves
// (2wm x 2wn), wave 64x64. Same counted-vmcnt schedule; A dma bf16, B reg-staged bf16.
// LDS 64KB -> 2 blocks/CU.
__global__ __launch_bounds__(256, 2) void gemm2_k(
    const unsigned short* __restrict__ hidden, const float* __restrict__ wd,
    const int* __restrict__ perm, const int* __restrict__ counts,
    const int* __restrict__ offsets, const int* __restrict__ tm2,
    const int* __restrict__ nt2, float* __restrict__ out) {
  const int t = blockIdx.x >> 3;
  const int nt = blockIdx.x & 7;           // siblings bid+=8 -> same XCD
  if (t >= *nt2) return;
  const int tm = tm2[t];
  const int e = tm >> 8, mt = tm & 255;
  const int ne = counts[e];
  const int off = offsets[e];

  __shared__ __align__(16) char lds[65536];  // A: P*16384; B: 32768 + P*16384

  const int tid = threadIdx.x;
  const int lane = tid & 63;
  const int wid = tid >> 6;
  const int wm = wid >> 1, wn = wid & 1;
  const int wrow = wm * 64, wcol = wn * 64;
  const int frow = lane & 15;
  const int fk = lane >> 4;

  const char* aSrc[4];
#pragma unroll
  for (int i = 0; i < 4; ++i) {
    const int row = wid * 32 + i * 8 + (lane >> 3);
    int lr = mt * 128 + row;
    const int gr = off + ((lr < ne) ? lr : (ne - 1));
    aSrc[i] = (const char*)hidden + (size_t)gr * 8192 + (((lane & 7) ^ (row & 7)) << 4);
  }
  const int brow = tid >> 1, bhalf = tid & 1;
  const float* bSrc = wd + ((size_t)e * HD + nt * 128 + brow) * ID + bhalf * 32;

  f32x4 acc[4][4] = {};
  f32x4 rB[8];

#define G2_LOADB(kt)                                                      \
  do {                                                                    \
    const float* s_ = bSrc + (kt) * 64;                                   \
    _Pragma("unroll") for (int i = 0; i < 8; ++i)                         \
      rB[i] = *(const f32x4*)(s_ + i * 4);                                \
  } while (0)

#define G2_WRITEB(P)                                                      \
  do {                                                                    \
    _Pragma("unroll") for (int i = 0; i < 4; ++i) {                       \
      const int ls_ = (bhalf * 4 + i) ^ (brow & 7);                       \
      *(bf16x8*)(lds + 32768 + (P) * 16384 + brow * 128 + (ls_ << 4)) =   \
          pack8(rB[2 * i], rB[2 * i + 1]);                                \
    }                                                                     \
  } while (0)

#define G2_ISSUE_A(kt, P)                                                 \
  do {                                                                    \
    _Pragma("unroll") for (int i = 0; i < 4; ++i)                         \
      dma16(aSrc[i] + (size_t)(kt) * 128, lds + (P) * 16384 + wid * 4096 + i * 1024); \
  } while (0)

#define G2_COMP(P)                                                        \
  do {                                                                    \
    _Pragma("unroll") for (int h = 0; h < 2; ++h) {                       \
      bf16x8 bb[4], af[4];                                                \
      _Pragma("unroll") for (int ni = 0; ni < 4; ++ni) {                  \
        const int rb_ = wcol + ni * 16 + frow;                            \
        bb[ni] = *(const bf16x8*)(lds + 32768 + (P) * 16384 + rb_ * 128 + \
                                  (((h * 4 + fk) ^ (rb_ & 7)) << 4));     \
      }                                                                   \
      _Pragma("unroll") for (int q = 0; q < 4; ++q) {                     \
        const int ra_ = wrow + q * 16 + frow;                             \
        af[q] = *(const bf16x8*)(lds + (P) * 16384 + ra_ * 128 +          \
                                 (((h * 4 + fk) ^ (ra_ & 7)) << 4));      \
      }                                                                   \
      __builtin_amdgcn_s_setprio(1);                                      \
      _Pragma("unroll") for (int q = 0; q < 4; ++q)                       \
        _Pragma("unroll") for (int ni = 0; ni < 4; ++ni)                  \
          acc[q][ni] = __builtin_amdgcn_mfma_f32_16x16x32_bf16(           \
              af[q], bb[ni], acc[q][ni], 0, 0, 0);                        \
      __builtin_amdgcn_s_setprio(0);                                      \
    }                                                                     \
  } while (0)

  const int NIT = ID / 64;  // 64
  G2_LOADB(0);
  G2_ISSUE_A(0, 0);
  G2_WRITEB(0);
  G2_LOADB(1);
  G2_ISSUE_A(1, 1);
  wait_vm12();
  bar_lgkm();

  for (int kt = 0; kt < NIT; ++kt) {
    const int P = kt & 1;
    if (kt + 1 < NIT) G2_WRITEB(P ^ 1);
    G2_COMP(P);
    if (kt + 2 < NIT) G2_LOADB(kt + 2);
    bar_lgkm();
    if (kt + 2 < NIT) {
      G2_ISSUE_A(kt + 2, P);
      wait_vm12();
    } else {
      wait_vm0();
    }
    __builtin_amdgcn_s_barrier();
  }
#undef G2_LOADB
#undef G2_WRITEB
#undef G2_ISSUE_A
#undef G2_COMP

#pragma unroll
  for (int q = 0; q < 4; ++q)
#pragma unroll
    for (int j = 0; j < 4; ++j) {
      const int row = wrow + q * 16 + fk * 4 + j;
      const int grow = mt * 128 + row;
      if (grow < ne) {
        const int tk = perm[off + grow];
        float* orow = out + (size_t)tk * HD + nt * 128 + wcol;
#pragma unroll
        for (int ni = 0; ni < 4; ++ni) orow[ni * 16 + frow] = acc[q][ni][j];
      }
    }
}

extern "C" void kernel_launch(void* const* d_in, const int* in_sizes, int n_in,
                              void* d_out, int out_size, void* d_ws, size_t ws_size,
                              hipStream_t stream) {
  const float* x  = (const float*)d_in[0];
  const float* gw = (const float*)d_in[1];
  const float* wg = (const float*)d_in[2];
  const float* wu = (const float*)d_in[3];
  const float* wd = (const float*)d_in[4];
  float* out = (float*)d_out;
  float* logits = out + (size_t)TOK * HD;

  unsigned short* hidden = (unsigned short*)d_ws;                       // 33.55 MB
  unsigned short* xp = (unsigned short*)((char*)d_ws + 33554432);       // 8.39 MB
  int* meta = (int*)((char*)d_ws + 33554432 + 8388608);
  int* counts  = meta;                  // [8]
  int* counts2 = meta + 8;              // [8]
  int* offsets = meta + 16;             // [8]
  int* tm1     = meta + 24;             // [MAXT1]
  int* nt1     = meta + 24 + MAXT1;     // [1]
  int* tm2     = meta + 25 + MAXT1;     // [MAXT2]
  int* nt2     = meta + 25 + MAXT1 + MAXT2;  // [1]
  int* top1    = meta + 26 + MAXT1 + MAXT2;  // [TOK]
  int* perm    = top1 + TOK;            // [TOK]

  init_k<<<1, 64, 0, stream>>>(meta);
  router_k<<<TOK / 4, 256, 0, stream>>>(x, gw, logits, top1);
  hist_k<<<TOK / 256, 256, 0, stream>>>(top1, counts);
  offsets_k<<<1, 64, 0, stream>>>(counts, offsets, tm1, nt1, tm2, nt2);
  scatter_k<<<TOK / 256, 256, 0, stream>>>(top1, offsets, counts2, perm);
  xp_k<<<TOK / 4, 256, 0, stream>>>(x, perm, xp);
  gemm1_k<<<MAXT1 * 32, 512, 0, stream>>>(xp, wg, wu, counts, offsets, tm1, nt1, hidden);
  gemm2_k<<<MAXT2 * 8, 256, 0, stream>>>(hidden, wd, perm, counts, offsets, tm2, nt2, out);
}